// Round 4
// baseline (2092.343 us; speedup 1.0000x reference)
//
#include <hip/hip_runtime.h>
#include <math.h>

// Problem constants (B=8, T=256 -> 2048 independent (b,t) pipelines)
// R10: occupancy unlock. R9 showed the kernel is cache-resident (HBM ~0%)
// and latency-bound at 31% occupancy (launch_bounds min_waves=3 pinned us
// at ~2.5 blocks/CU while VGPR=76 permits 6 waves/SIMD). Single change:
// __launch_bounds__(256, 6) -> VGPR cap 85 >= 76 used (no spill risk),
// 6 blocks/CU, ~2x concurrency. Everything else byte-identical to R9.
#define NBT 2048

typedef __attribute__((ext_vector_type(8))) short short8;     // 8 bf16 (4 VGPRs)
typedef __attribute__((ext_vector_type(4))) float floatx4;    // MFMA C/D

struct SM {
  alignas(16) float xp[240];        // zero-padded encoder input (nonzero in [80,160))
  alignas(16) unsigned xhl[256];    // packed bf16: hi | lo<<16, zero-padded to 256
  alignas(16) float hsq[256];       // h^2 for top-64 ranking
  alignas(16) float yres[80];
  alignas(16) float beL[256];       // encoder bias staged in LDS
  alignas(16) float spad[240];      // padded buffer for sim windows
  alignas(16) float dval[64];       // compacted selected hidden values (ascending idx)
  alignas(16) int   dlist[64];      // compacted selected hidden indices (ascending)
  alignas(16) float energyP[4][96]; // per-wave (per-ng) energy partials
  float xres[80];
  float yal[80];
  float xele[80];
  float decsrc[80];
  float zb[80];
  float energy[96];                 // 81 valid + pad (6 m-tiles of 16)
  float mp_self[256];
  float mp_src[256];
  float ext[160];
  unsigned char smask[80];
  int smask_t;
  // cross-wave scratch
  float abv[4];
  int   abi[4];
  int   wcnt[4];
  float nys;
};

// ---- wave-level primitives (64 lanes, butterfly -> all lanes hold result) ----
__device__ __forceinline__ float waveSum(float v){
  #pragma unroll
  for (int off = 32; off > 0; off >>= 1) v += __shfl_xor(v, off, 64);
  return v;
}
__device__ __forceinline__ int waveSumI(int v){
  #pragma unroll
  for (int off = 32; off > 0; off >>= 1) v += __shfl_xor(v, off, 64);
  return v;
}
__device__ __forceinline__ float waveMax(float v){
  #pragma unroll
  for (int off = 32; off > 0; off >>= 1) v = fmaxf(v, __shfl_xor(v, off, 64));
  return v;
}

// block-wide argmax, JAX tie rule (lowest index wins). Max + min-index is
// associative, so any reduction structure yields the unique answer.
// All 256 threads must call; all return the winning index.
__device__ __forceinline__ int blockArgMax(SM& sm, float v, int idx){
  int lane = threadIdx.x & 63, w = threadIdx.x >> 6;
  #pragma unroll
  for (int off = 32; off > 0; off >>= 1){
    float ov = __shfl_xor(v,   off, 64);
    int   oi = __shfl_xor(idx, off, 64);
    if (ov > v || (ov == v && oi < idx)){ v = ov; idx = oi; }
  }
  if (lane == 0){ sm.abv[w] = v; sm.abi[w] = idx; }
  __syncthreads();
  float bv = sm.abv[0]; int bi = sm.abi[0];
  #pragma unroll
  for (int w2 = 1; w2 < 4; w2++){
    float ov = sm.abv[w2]; int oi = sm.abi[w2];
    if (ov > bv || (ov == bv && oi < bi)){ bv = ov; bi = oi; }
  }
  __syncthreads();   // abv/abi free for reuse after this
  return bi;
}

// top-64 membership via rank for this thread's hidden unit j = tid.
// rank = #{i: v_i > v_j} + #{i<j: v_i == v_j}; selected iff rank < 64.
// hsq[i4] reads are block-uniform -> LDS broadcast, conflict-free. Integer: exact.
__device__ __forceinline__ int rankTop64(SM& sm, float vsq, int j){
  int cnt = 0;
  const float4* q4 = (const float4*)sm.hsq;
  #pragma unroll 4
  for (int i4 = 0; i4 < 64; i4++){
    float4 o = q4[i4];
    int ib = i4 * 4;
    cnt += (o.x > vsq || (o.x == vsq && (ib + 0) < j)) ? 1 : 0;
    cnt += (o.y > vsq || (o.y == vsq && (ib + 1) < j)) ? 1 : 0;
    cnt += (o.z > vsq || (o.z == vsq && (ib + 2) < j)) ? 1 : 0;
    cnt += (o.w > vsq || (o.w == vsq && (ib + 3) < j)) ? 1 : 0;
  }
  return (cnt < 64) ? 1 : 0;
}

// Compact the exactly-64 selected (index,value) pairs into ascending-index LDS
// lists: per-wave ballot + cross-wave popcount prefix. Ascending order =>
// decode accumulation order matches the reference bit-exactly.
__device__ __forceinline__ void compactSel(SM& sm, int sel, float val){
  int tid = threadIdx.x, lane = tid & 63, w = tid >> 6;
  unsigned long long mq = __ballot(sel != 0);
  if (lane == 0) sm.wcnt[w] = __popcll(mq);
  __syncthreads();
  int base = 0;
  #pragma unroll
  for (int i = 0; i < 4; i++) base += (i < w) ? sm.wcnt[i] : 0;
  if (sel){
    unsigned long long below = (lane == 0) ? 0ull : ((~0ull) >> (64 - lane));
    int pos = base + (int)__popcll(mq & below);
    sm.dlist[pos] = tid;
    sm.dval[pos]  = val;
  }
  __syncthreads();   // list ready
}

// sim_argmax: cosine sim over 159 shifts of src vs yres; thread t owns shift t.
// Per-shift fmaf chain order identical to legacy (bit-exact sims). nys is
// computed by wave 0 with the legacy butterfly (bit-exact).
__device__ __forceinline__ int simArgmax(SM& sm, const float* src, float* yal_out){
  int tid = threadIdx.x;
  int lane = tid & 63, w = tid >> 6;
  __syncthreads();
  if (tid < 240) sm.spad[tid] = (tid >= 79 && tid < 159) ? src[tid - 79] : 0.f;
  if (w == 0){
    float yv2 = 0.f;
    for (int i = lane; i < 80; i += 64){ float yv = sm.yres[i]; yv2 = fmaf(yv, yv, yv2); }
    float ny = sqrtf(waveSum(yv2));
    if (lane == 0) sm.nys = ny;
  }
  __syncthreads();
  float nys = sm.nys;
  float bv = -INFINITY; int bi = 0;
  if (tid < 159){
    const float4* y4p = (const float4*)sm.yres;
    float num = 0.f, nx = 0.f;
    for (int w4 = 0; w4 < 20; w4++){
      float4 yy = y4p[w4];
      int wb = w4 * 4;
      float xa0 = sm.spad[tid + wb + 0];
      float xa1 = sm.spad[tid + wb + 1];
      float xa2 = sm.spad[tid + wb + 2];
      float xa3 = sm.spad[tid + wb + 3];
      num = fmaf(xa0, yy.x, num); nx = fmaf(xa0, xa0, nx);
      num = fmaf(xa1, yy.y, num); nx = fmaf(xa1, xa1, nx);
      num = fmaf(xa2, yy.z, num); nx = fmaf(xa2, xa2, nx);
      num = fmaf(xa3, yy.w, num); nx = fmaf(xa3, xa3, nx);
    }
    bv = num / (sqrtf(nx) * nys + 1e-6f);
    bi = tid;
  }
  int th = blockArgMax(sm, bv, bi);
  if (tid < 80) yal_out[tid] = sm.spad[th + tid];
  __syncthreads();
  return th;
}

// One branch: MFMA energy (split bf16, kt-trimmed — bit-safe; wave w owns
// n-group w, partials summed in legacy ng order; B-frags streamed per n-tile
// to keep peak live registers below the spill line), argmax, exact fp32 row
// recompute (1 j/thread), hsr, sparse decode (1 d/thread), masked loss.
template<int USE_WS>
__device__ __forceinline__ void branchCompute(
    SM& sm, const float* __restrict__ We,
    const short8* __restrict__ wsBh, const short8* __restrict__ wsBl,
    const float* __restrict__ Wdec, const float* __restrict__ bdec,
    const float* enc_in, float* mask, const float* target,
    float* dec_out, int theta, bool first, float& lossAcc)
{
  int tid = threadIdx.x;
  int lane = tid & 63, w = tid >> 6;
  int quad = lane >> 4, l15 = lane & 15;
  __syncthreads();
  {
    float v = (tid >= 80 && tid < 160) ? enc_in[tid - 80] : 0.f;
    if (tid < 240) sm.xp[tid] = v;
    unsigned bits = __float_as_uint(v);
    unsigned hi = bits >> 16;
    float hif = __uint_as_float(hi << 16);
    unsigned lo = __float_as_uint(v - hif) >> 16;
    sm.xhl[tid] = hi | (lo << 16);
  }
  __syncthreads();

  const floatx4 zero4 = {0.f, 0.f, 0.f, 0.f};
  const int ng = w;                  // wave w owns n-group w (4 n-tiles)

  #pragma unroll 1
  for (int mh = 0; mh < 3; mh++){    // 2 m-tiles per pass
    int ktlo = (mh == 0) ? 1 : 0;    // nonzero-support kt range for these m rows
    int kthi = 5 - mh;               // (skipped products are exactly 0 -> bit-safe)
    floatx4 acc[2][4];
    #pragma unroll
    for (int m2 = 0; m2 < 2; m2++)
      #pragma unroll
      for (int nt = 0; nt < 4; nt++) acc[m2][nt] = zero4;

    #pragma unroll 1
    for (int kt = ktlo; kt < kthi; kt++){
      // A fragments for this kt, both m-tiles (held across the nt stream)
      short8 Ah[2], Al[2];
      #pragma unroll
      for (int m2 = 0; m2 < 2; m2++){
        int mt = mh * 2 + m2;
        int base = mt * 16 + l15 + kt * 32 + quad * 8;
        short8 ah, al;
        #pragma unroll
        for (int j = 0; j < 8; j++){
          unsigned u = sm.xhl[base + j];
          ah[j] = (short)(u & 0xffffu);
          al[j] = (short)(u >> 16);
        }
        Ah[m2] = ah; Al[m2] = al;
      }
      // stream B per n-tile: only one (Bh,Bl) pair live at a time (x2 unroll)
      #pragma unroll 2
      for (int nt = 0; nt < 4; nt++){
        short8 Bh, Bl;
        int tileIdx = kt * 16 + (ng * 4 + nt);
        if (USE_WS){
          Bh = wsBh[tileIdx * 64 + lane];
          Bl = wsBl[tileIdx * 64 + lane];
        } else {
          short8 bh, bl;
          int k0 = kt * 32 + quad * 8;
          int n  = (ng * 4 + nt) * 16 + l15;
          #pragma unroll
          for (int j = 0; j < 8; j++){
            float v = We[(k0 + j) * 256 + n];
            unsigned bits = __float_as_uint(v);
            unsigned hi = bits >> 16;
            float hif = __uint_as_float(hi << 16);
            unsigned lo = __float_as_uint(v - hif) >> 16;
            bh[j] = (short)hi; bl[j] = (short)lo;
          }
          Bh = bh; Bl = bl;
        }
        // per-accumulator op order unchanged vs legacy: AhBh, AlBh, AhBl
        acc[0][nt] = __builtin_amdgcn_mfma_f32_16x16x32_bf16(Ah[0], Bh, acc[0][nt], 0, 0, 0);
        acc[0][nt] = __builtin_amdgcn_mfma_f32_16x16x32_bf16(Al[0], Bh, acc[0][nt], 0, 0, 0);
        acc[0][nt] = __builtin_amdgcn_mfma_f32_16x16x32_bf16(Ah[0], Bl, acc[0][nt], 0, 0, 0);
        acc[1][nt] = __builtin_amdgcn_mfma_f32_16x16x32_bf16(Ah[1], Bh, acc[1][nt], 0, 0, 0);
        acc[1][nt] = __builtin_amdgcn_mfma_f32_16x16x32_bf16(Al[1], Bh, acc[1][nt], 0, 0, 0);
        acc[1][nt] = __builtin_amdgcn_mfma_f32_16x16x32_bf16(Ah[1], Bl, acc[1][nt], 0, 0, 0);
      }
    }

    // epilogue: add bias, square, reduce this wave's 64 columns (l15 butterfly,
    // byte-identical to legacy per-ng computation)
    float bn[4];
    #pragma unroll
    for (int nt = 0; nt < 4; nt++) bn[nt] = sm.beL[(ng * 4 + nt) * 16 + l15];
    #pragma unroll
    for (int m2 = 0; m2 < 2; m2++){
      int mt = mh * 2 + m2;
      float er[4];
      #pragma unroll
      for (int r = 0; r < 4; r++){
        float s_ = 0.f;
        #pragma unroll
        for (int nt = 0; nt < 4; nt++){
          float hvv = acc[m2][nt][r] + bn[nt];
          s_ = fmaf(hvv, hvv, s_);
        }
        er[r] = s_;
      }
      #pragma unroll
      for (int x2 = 1; x2 < 16; x2 <<= 1){
        #pragma unroll
        for (int r = 0; r < 4; r++) er[r] += __shfl_xor(er[r], x2, 64);
      }
      if (l15 == 0){
        #pragma unroll
        for (int r = 0; r < 4; r++)
          sm.energyP[w][mt * 16 + quad * 4 + r] = er[r];
      }
    }
  }
  __syncthreads();
  // combine ng partials in legacy left-assoc ng order: (((ng0+ng1)+ng2)+ng3)
  if (tid < 96){
    float e = sm.energyP[0][tid];
    e += sm.energyP[1][tid];
    e += sm.energyP[2][tid];
    e += sm.energyP[3][tid];
    sm.energy[tid] = e;
  }
  __syncthreads();

  // argmax over 81 energies (padded rows >80 contain garbage — exclude them)
  float bvE = (tid < 81) ? sm.energy[tid] : -INFINITY;
  int   biE = (tid < 81) ? tid : 0;
  int ind = blockArgMax(sm, bvE, biE);

  // recompute selected row h[ind, j] EXACTLY in fp32; thread owns j = tid
  // (same per-j fmaf chain order as legacy -> bit-exact)
  int roff = 80 - ind;
  float hv = sm.beL[tid];
  #pragma unroll 4
  for (int w2 = 0; w2 < 80; w2++){
    float xv = sm.xp[80 + w2];
    hv = fmaf(xv, We[(w2 + roff) * 256 + tid], hv);
  }

  // hsr (thread's single j)
  float vsq = hv * hv;
  sm.hsq[tid] = vsq;
  __syncthreads();
  int sel1 = rankTop64(sm, vsq, tid);
  float mpv = mask[tid];
  if (first){
    mask[tid] = (float)sel1;
    compactSel(sm, sel1, hv);
  } else {
    int st = sm.smask_t;
    float interv = mpv * (float)sel1;
    if (interv > 0.f && !st){
      float dd = hv - (1.f - interv);
      lossAcc += dd * dd;
    }
    float h2 = (mpv > 0.f) ? 0.f : hv;
    __syncthreads();               // rank1 readers done before hsq rewrite
    sm.hsq[tid] = h2 * h2;
    __syncthreads();
    int sel2 = rankTop64(sm, h2 * h2, tid);
    mask[tid] = mpv + (float)sel2;
    compactSel(sm, sel2, h2);
  }
  // compactSel ends with a barrier -> dlist/dval ready

  // sparse decode over the exactly-64 selected rows (ascending idx => bit-exact):
  // ext[d] = bdec[d] + sum_{sel h asc} val_h * Wdec[h*160+d]; thread owns d = tid
  if (tid < 160){
    float a = bdec[tid];
    #pragma unroll 8
    for (int i = 0; i < 64; i++){
      int idx = sm.dlist[i];       // block-uniform broadcast
      float hval = sm.dval[i];
      a = fmaf(hval, Wdec[idx * 160 + tid], a);
    }
    sm.ext[tid] = a;
  }
  __syncthreads();

  float mv = fabsf((float)(theta - 79));
  bool gate = (mv > 40.0f);        // ETH
  if (tid < 80){
    float dec = sm.ext[ind + tid];
    dec_out[tid] = dec;            // residual update uses decoded output regardless of gates
    float diff = dec - target[tid];
    float l = (gate || sm.smask[tid]) ? 0.f : diff * diff;
    lossAcc += l / (mv + 1.0f);
  }
  __syncthreads();
}

__global__ void __launch_bounds__(64) zero_out_kernel(float* out){
  if (threadIdx.x == 0) out[0] = 0.f;
}

// Pre-repack We into MFMA B-fragment layout (bf16 hi and lo), one 16B frag per lane per tile.
__global__ void __launch_bounds__(64) prep_we_kernel(
    const float* __restrict__ We, short8* __restrict__ bh, short8* __restrict__ bl){
  int tile = blockIdx.x;
  int lane = threadIdx.x;
  int kt = tile >> 4, nt = tile & 15;
  int k0 = kt * 32 + (lane >> 4) * 8;
  int n  = nt * 16 + (lane & 15);
  short8 h, l;
  #pragma unroll
  for (int j = 0; j < 8; j++){
    float v = We[(k0 + j) * 256 + n];
    unsigned bits = __float_as_uint(v);
    unsigned hi = bits >> 16;
    float hif = __uint_as_float(hi << 16);
    unsigned lo = __float_as_uint(v - hif) >> 16;
    h[j] = (short)hi; l[j] = (short)lo;
  }
  bh[tile * 64 + lane] = h;
  bl[tile * 64 + lane] = l;
}

template<int USE_WS>
__global__ void __launch_bounds__(256, 6) net_kernel(
    const float* __restrict__ x,  const float* __restrict__ y,
    const float* __restrict__ We, const float* __restrict__ be,
    const float* __restrict__ Wd, const float* __restrict__ bd,
    const float* __restrict__ Wds,const float* __restrict__ bds,
    const short8* __restrict__ wsBh, const short8* __restrict__ wsBl,
    float* out)
{
  __shared__ SM sm;
  int tid = threadIdx.x;
  int lane = tid & 63, w = tid >> 6;
  int bt  = blockIdx.x;
  const float* xin = x + bt * 80;
  const float* yin = y + bt * 80;

  if (tid < 80){
    sm.xres[tid] = xin[tid];
    float yv = yin[tid];
    sm.yres[tid] = yv;
    sm.smask[tid] = (yv == 0.f) ? 1 : 0;   // seq_mask from ORIGINAL y
  }
  sm.mp_self[tid] = 0.f;
  sm.mp_src[tid]  = 0.f;
  sm.beL[tid] = be[tid];
  __syncthreads();
  if (w == 0){
    int c = 0;
    for (int i = lane; i < 80; i += 64) c += (int)sm.smask[i];
    int total = waveSumI(c);
    if (lane == 0) sm.smask_t = (total == 80) ? 1 : 0;
  }
  __syncthreads();

  float lossAcc = 0.f;

  for (int it = 0; it < 4; it++){
    bool first = (it == 0);

    // --- align x_res to y_res ---
    int th1 = simArgmax(sm, sm.xres, sm.yal);

    // --- attention softmax(y_al * y_res) and z = y_al * attn ---
    // order-sensitive sum: wave 0 runs the byte-identical legacy code
    if (w == 0){
      float p0 = sm.yal[lane] * sm.yres[lane];
      float p1 = (lane < 16) ? sm.yal[64 + lane] * sm.yres[64 + lane] : -INFINITY;
      float mx = waveMax(fmaxf(p0, p1));
      float e0 = expf(p0 - mx);
      float e1 = (lane < 16) ? expf(p1 - mx) : 0.f;
      float ssum = waveSum(e0 + e1);
      sm.zb[lane] = sm.yal[lane] * (e0 / ssum);
      if (lane < 16) sm.zb[64 + lane] = sm.yal[64 + lane] * (e1 / ssum);
    }
    __syncthreads();

    // --- reverse shift: x_ele[d] = z[d + 79 - theta] ---
    if (tid < 80){
      int q = tid + 79 - th1;
      sm.xele[tid] = (q >= 0 && q < 80) ? sm.zb[q] : 0.f;
    }

    // --- self branch ---
    branchCompute<USE_WS>(sm, We, wsBh, wsBl, Wds, bds,
                          sm.xele, sm.mp_self, sm.xres, sm.xele, th1, first, lossAcc);

    // --- re-align decoded x_ele to y_res ---
    int th2 = simArgmax(sm, sm.xele, sm.yal);

    // --- src branch ---
    branchCompute<USE_WS>(sm, We, wsBh, wsBl, Wd, bd,
                          sm.yal, sm.mp_src, sm.yres, sm.decsrc, th2, first, lossAcc);

    // --- residual updates ---
    __syncthreads();
    if (tid < 80){
      sm.xres[tid] -= sm.xele[tid];
      sm.yres[tid] -= sm.decsrc[tid];
    }
    __syncthreads();
  }

  // block loss reduction: per-wave butterfly, then fixed-order 4-way sum
  float vsum = waveSum(lossAcc);
  if (lane == 0) sm.abv[w] = vsum;
  __syncthreads();
  if (tid == 0){
    float total = ((sm.abv[0] + sm.abv[1]) + sm.abv[2]) + sm.abv[3];
    atomicAdd(out, total * 0.25f);   // mean over 4 iterations
  }
}

extern "C" void kernel_launch(void* const* d_in, const int* in_sizes, int n_in,
                              void* d_out, int out_size, void* d_ws, size_t ws_size,
                              hipStream_t stream) {
  const float* x   = (const float*)d_in[0];
  const float* y   = (const float*)d_in[1];
  const float* We  = (const float*)d_in[2];
  const float* be  = (const float*)d_in[3];
  const float* Wd  = (const float*)d_in[4];
  const float* bd  = (const float*)d_in[5];
  const float* Wds = (const float*)d_in[6];
  const float* bds = (const float*)d_in[7];
  float* out = (float*)d_out;

  // We-fragment repack buffers: 80 tiles x 64 lanes x 16B each for hi and lo
  const size_t fragCount = 80 * 64;                     // short8 elements per buffer
  const size_t fragBytes = fragCount * sizeof(short8);  // 81920 B
  int use_ws = (ws_size >= 2 * fragBytes) ? 1 : 0;
  short8* wsBh = (short8*)d_ws;
  short8* wsBl = wsBh + fragCount;

  hipLaunchKernelGGL(zero_out_kernel, dim3(1), dim3(64), 0, stream, out);
  if (use_ws){
    hipLaunchKernelGGL(prep_we_kernel, dim3(80), dim3(64), 0, stream, We, wsBh, wsBl);
    hipLaunchKernelGGL((net_kernel<1>), dim3(NBT), dim3(256), 0, stream,
                       x, y, We, be, Wd, bd, Wds, bds, wsBh, wsBl, out);
  } else {
    hipLaunchKernelGGL((net_kernel<0>), dim3(NBT), dim3(256), 0, stream,
                       x, y, We, be, Wd, bd, Wds, bds, wsBh, wsBl, out);
  }
}

// Round 5
// 803.174 us; speedup vs baseline: 2.6051x; 2.6051x over previous
//
#include <hip/hip_runtime.h>
#include <math.h>

// Problem constants (B=8, T=256 -> 2048 independent (b,t) pipelines)
// R11: occupancy ladder, safe rung. Evidence so far:
//   bound=3 -> budget 170, uses 76, no spill, 3 blk/CU, 920 us   (R9)
//   bound=6 -> HW VGPR quantum forced unified budget to 64 -> 5.9 GB
//              scratch traffic, 2.1 ms                            (R10)
// The HW grants waves at coarse VGPR steps (64/128/256), so min_waves=6
// means a 64-reg budget -- far below the ~76 this structure needs.
// bound=4 -> budget 128 >= 76 with headroom: no spill possible, and
// 4 blocks/CU (16 waves/CU) vs R9's 3. Body is byte-identical to R9.
#define NBT 2048

typedef __attribute__((ext_vector_type(8))) short short8;     // 8 bf16 (4 VGPRs)
typedef __attribute__((ext_vector_type(4))) float floatx4;    // MFMA C/D

struct SM {
  alignas(16) float xp[240];        // zero-padded encoder input (nonzero in [80,160))
  alignas(16) unsigned xhl[256];    // packed bf16: hi | lo<<16, zero-padded to 256
  alignas(16) float hsq[256];       // h^2 for top-64 ranking
  alignas(16) float yres[80];
  alignas(16) float beL[256];       // encoder bias staged in LDS
  alignas(16) float spad[240];      // padded buffer for sim windows
  alignas(16) float dval[64];       // compacted selected hidden values (ascending idx)
  alignas(16) int   dlist[64];      // compacted selected hidden indices (ascending)
  alignas(16) float energyP[4][96]; // per-wave (per-ng) energy partials
  float xres[80];
  float yal[80];
  float xele[80];
  float decsrc[80];
  float zb[80];
  float energy[96];                 // 81 valid + pad (6 m-tiles of 16)
  float mp_self[256];
  float mp_src[256];
  float ext[160];
  unsigned char smask[80];
  int smask_t;
  // cross-wave scratch
  float abv[4];
  int   abi[4];
  int   wcnt[4];
  float nys;
};

// ---- wave-level primitives (64 lanes, butterfly -> all lanes hold result) ----
__device__ __forceinline__ float waveSum(float v){
  #pragma unroll
  for (int off = 32; off > 0; off >>= 1) v += __shfl_xor(v, off, 64);
  return v;
}
__device__ __forceinline__ int waveSumI(int v){
  #pragma unroll
  for (int off = 32; off > 0; off >>= 1) v += __shfl_xor(v, off, 64);
  return v;
}
__device__ __forceinline__ float waveMax(float v){
  #pragma unroll
  for (int off = 32; off > 0; off >>= 1) v = fmaxf(v, __shfl_xor(v, off, 64));
  return v;
}

// block-wide argmax, JAX tie rule (lowest index wins). Max + min-index is
// associative, so any reduction structure yields the unique answer.
// All 256 threads must call; all return the winning index.
__device__ __forceinline__ int blockArgMax(SM& sm, float v, int idx){
  int lane = threadIdx.x & 63, w = threadIdx.x >> 6;
  #pragma unroll
  for (int off = 32; off > 0; off >>= 1){
    float ov = __shfl_xor(v,   off, 64);
    int   oi = __shfl_xor(idx, off, 64);
    if (ov > v || (ov == v && oi < idx)){ v = ov; idx = oi; }
  }
  if (lane == 0){ sm.abv[w] = v; sm.abi[w] = idx; }
  __syncthreads();
  float bv = sm.abv[0]; int bi = sm.abi[0];
  #pragma unroll
  for (int w2 = 1; w2 < 4; w2++){
    float ov = sm.abv[w2]; int oi = sm.abi[w2];
    if (ov > bv || (ov == bv && oi < bi)){ bv = ov; bi = oi; }
  }
  __syncthreads();   // abv/abi free for reuse after this
  return bi;
}

// top-64 membership via rank for this thread's hidden unit j = tid.
// rank = #{i: v_i > v_j} + #{i<j: v_i == v_j}; selected iff rank < 64.
// hsq[i4] reads are block-uniform -> LDS broadcast, conflict-free. Integer: exact.
__device__ __forceinline__ int rankTop64(SM& sm, float vsq, int j){
  int cnt = 0;
  const float4* q4 = (const float4*)sm.hsq;
  #pragma unroll 4
  for (int i4 = 0; i4 < 64; i4++){
    float4 o = q4[i4];
    int ib = i4 * 4;
    cnt += (o.x > vsq || (o.x == vsq && (ib + 0) < j)) ? 1 : 0;
    cnt += (o.y > vsq || (o.y == vsq && (ib + 1) < j)) ? 1 : 0;
    cnt += (o.z > vsq || (o.z == vsq && (ib + 2) < j)) ? 1 : 0;
    cnt += (o.w > vsq || (o.w == vsq && (ib + 3) < j)) ? 1 : 0;
  }
  return (cnt < 64) ? 1 : 0;
}

// Compact the exactly-64 selected (index,value) pairs into ascending-index LDS
// lists: per-wave ballot + cross-wave popcount prefix. Ascending order =>
// decode accumulation order matches the reference bit-exactly.
__device__ __forceinline__ void compactSel(SM& sm, int sel, float val){
  int tid = threadIdx.x, lane = tid & 63, w = tid >> 6;
  unsigned long long mq = __ballot(sel != 0);
  if (lane == 0) sm.wcnt[w] = __popcll(mq);
  __syncthreads();
  int base = 0;
  #pragma unroll
  for (int i = 0; i < 4; i++) base += (i < w) ? sm.wcnt[i] : 0;
  if (sel){
    unsigned long long below = (lane == 0) ? 0ull : ((~0ull) >> (64 - lane));
    int pos = base + (int)__popcll(mq & below);
    sm.dlist[pos] = tid;
    sm.dval[pos]  = val;
  }
  __syncthreads();   // list ready
}

// sim_argmax: cosine sim over 159 shifts of src vs yres; thread t owns shift t.
// Per-shift fmaf chain order identical to legacy (bit-exact sims). nys is
// computed by wave 0 with the legacy butterfly (bit-exact).
__device__ __forceinline__ int simArgmax(SM& sm, const float* src, float* yal_out){
  int tid = threadIdx.x;
  int lane = tid & 63, w = tid >> 6;
  __syncthreads();
  if (tid < 240) sm.spad[tid] = (tid >= 79 && tid < 159) ? src[tid - 79] : 0.f;
  if (w == 0){
    float yv2 = 0.f;
    for (int i = lane; i < 80; i += 64){ float yv = sm.yres[i]; yv2 = fmaf(yv, yv, yv2); }
    float ny = sqrtf(waveSum(yv2));
    if (lane == 0) sm.nys = ny;
  }
  __syncthreads();
  float nys = sm.nys;
  float bv = -INFINITY; int bi = 0;
  if (tid < 159){
    const float4* y4p = (const float4*)sm.yres;
    float num = 0.f, nx = 0.f;
    for (int w4 = 0; w4 < 20; w4++){
      float4 yy = y4p[w4];
      int wb = w4 * 4;
      float xa0 = sm.spad[tid + wb + 0];
      float xa1 = sm.spad[tid + wb + 1];
      float xa2 = sm.spad[tid + wb + 2];
      float xa3 = sm.spad[tid + wb + 3];
      num = fmaf(xa0, yy.x, num); nx = fmaf(xa0, xa0, nx);
      num = fmaf(xa1, yy.y, num); nx = fmaf(xa1, xa1, nx);
      num = fmaf(xa2, yy.z, num); nx = fmaf(xa2, xa2, nx);
      num = fmaf(xa3, yy.w, num); nx = fmaf(xa3, xa3, nx);
    }
    bv = num / (sqrtf(nx) * nys + 1e-6f);
    bi = tid;
  }
  int th = blockArgMax(sm, bv, bi);
  if (tid < 80) yal_out[tid] = sm.spad[th + tid];
  __syncthreads();
  return th;
}

// One branch: MFMA energy (split bf16, kt-trimmed — bit-safe; wave w owns
// n-group w, partials summed in legacy ng order; B-frags streamed per n-tile
// to keep peak live registers below the spill line), argmax, exact fp32 row
// recompute (1 j/thread), hsr, sparse decode (1 d/thread), masked loss.
template<int USE_WS>
__device__ __forceinline__ void branchCompute(
    SM& sm, const float* __restrict__ We,
    const short8* __restrict__ wsBh, const short8* __restrict__ wsBl,
    const float* __restrict__ Wdec, const float* __restrict__ bdec,
    const float* enc_in, float* mask, const float* target,
    float* dec_out, int theta, bool first, float& lossAcc)
{
  int tid = threadIdx.x;
  int lane = tid & 63, w = tid >> 6;
  int quad = lane >> 4, l15 = lane & 15;
  __syncthreads();
  {
    float v = (tid >= 80 && tid < 160) ? enc_in[tid - 80] : 0.f;
    if (tid < 240) sm.xp[tid] = v;
    unsigned bits = __float_as_uint(v);
    unsigned hi = bits >> 16;
    float hif = __uint_as_float(hi << 16);
    unsigned lo = __float_as_uint(v - hif) >> 16;
    sm.xhl[tid] = hi | (lo << 16);
  }
  __syncthreads();

  const floatx4 zero4 = {0.f, 0.f, 0.f, 0.f};
  const int ng = w;                  // wave w owns n-group w (4 n-tiles)

  #pragma unroll 1
  for (int mh = 0; mh < 3; mh++){    // 2 m-tiles per pass
    int ktlo = (mh == 0) ? 1 : 0;    // nonzero-support kt range for these m rows
    int kthi = 5 - mh;               // (skipped products are exactly 0 -> bit-safe)
    floatx4 acc[2][4];
    #pragma unroll
    for (int m2 = 0; m2 < 2; m2++)
      #pragma unroll
      for (int nt = 0; nt < 4; nt++) acc[m2][nt] = zero4;

    #pragma unroll 1
    for (int kt = ktlo; kt < kthi; kt++){
      // A fragments for this kt, both m-tiles (held across the nt stream)
      short8 Ah[2], Al[2];
      #pragma unroll
      for (int m2 = 0; m2 < 2; m2++){
        int mt = mh * 2 + m2;
        int base = mt * 16 + l15 + kt * 32 + quad * 8;
        short8 ah, al;
        #pragma unroll
        for (int j = 0; j < 8; j++){
          unsigned u = sm.xhl[base + j];
          ah[j] = (short)(u & 0xffffu);
          al[j] = (short)(u >> 16);
        }
        Ah[m2] = ah; Al[m2] = al;
      }
      // stream B per n-tile: only one (Bh,Bl) pair live at a time (x2 unroll)
      #pragma unroll 2
      for (int nt = 0; nt < 4; nt++){
        short8 Bh, Bl;
        int tileIdx = kt * 16 + (ng * 4 + nt);
        if (USE_WS){
          Bh = wsBh[tileIdx * 64 + lane];
          Bl = wsBl[tileIdx * 64 + lane];
        } else {
          short8 bh, bl;
          int k0 = kt * 32 + quad * 8;
          int n  = (ng * 4 + nt) * 16 + l15;
          #pragma unroll
          for (int j = 0; j < 8; j++){
            float v = We[(k0 + j) * 256 + n];
            unsigned bits = __float_as_uint(v);
            unsigned hi = bits >> 16;
            float hif = __uint_as_float(hi << 16);
            unsigned lo = __float_as_uint(v - hif) >> 16;
            bh[j] = (short)hi; bl[j] = (short)lo;
          }
          Bh = bh; Bl = bl;
        }
        // per-accumulator op order unchanged vs legacy: AhBh, AlBh, AhBl
        acc[0][nt] = __builtin_amdgcn_mfma_f32_16x16x32_bf16(Ah[0], Bh, acc[0][nt], 0, 0, 0);
        acc[0][nt] = __builtin_amdgcn_mfma_f32_16x16x32_bf16(Al[0], Bh, acc[0][nt], 0, 0, 0);
        acc[0][nt] = __builtin_amdgcn_mfma_f32_16x16x32_bf16(Ah[0], Bl, acc[0][nt], 0, 0, 0);
        acc[1][nt] = __builtin_amdgcn_mfma_f32_16x16x32_bf16(Ah[1], Bh, acc[1][nt], 0, 0, 0);
        acc[1][nt] = __builtin_amdgcn_mfma_f32_16x16x32_bf16(Al[1], Bh, acc[1][nt], 0, 0, 0);
        acc[1][nt] = __builtin_amdgcn_mfma_f32_16x16x32_bf16(Ah[1], Bl, acc[1][nt], 0, 0, 0);
      }
    }

    // epilogue: add bias, square, reduce this wave's 64 columns (l15 butterfly,
    // byte-identical to legacy per-ng computation)
    float bn[4];
    #pragma unroll
    for (int nt = 0; nt < 4; nt++) bn[nt] = sm.beL[(ng * 4 + nt) * 16 + l15];
    #pragma unroll
    for (int m2 = 0; m2 < 2; m2++){
      int mt = mh * 2 + m2;
      float er[4];
      #pragma unroll
      for (int r = 0; r < 4; r++){
        float s_ = 0.f;
        #pragma unroll
        for (int nt = 0; nt < 4; nt++){
          float hvv = acc[m2][nt][r] + bn[nt];
          s_ = fmaf(hvv, hvv, s_);
        }
        er[r] = s_;
      }
      #pragma unroll
      for (int x2 = 1; x2 < 16; x2 <<= 1){
        #pragma unroll
        for (int r = 0; r < 4; r++) er[r] += __shfl_xor(er[r], x2, 64);
      }
      if (l15 == 0){
        #pragma unroll
        for (int r = 0; r < 4; r++)
          sm.energyP[w][mt * 16 + quad * 4 + r] = er[r];
      }
    }
  }
  __syncthreads();
  // combine ng partials in legacy left-assoc ng order: (((ng0+ng1)+ng2)+ng3)
  if (tid < 96){
    float e = sm.energyP[0][tid];
    e += sm.energyP[1][tid];
    e += sm.energyP[2][tid];
    e += sm.energyP[3][tid];
    sm.energy[tid] = e;
  }
  __syncthreads();

  // argmax over 81 energies (padded rows >80 contain garbage — exclude them)
  float bvE = (tid < 81) ? sm.energy[tid] : -INFINITY;
  int   biE = (tid < 81) ? tid : 0;
  int ind = blockArgMax(sm, bvE, biE);

  // recompute selected row h[ind, j] EXACTLY in fp32; thread owns j = tid
  // (same per-j fmaf chain order as legacy -> bit-exact)
  int roff = 80 - ind;
  float hv = sm.beL[tid];
  #pragma unroll 4
  for (int w2 = 0; w2 < 80; w2++){
    float xv = sm.xp[80 + w2];
    hv = fmaf(xv, We[(w2 + roff) * 256 + tid], hv);
  }

  // hsr (thread's single j)
  float vsq = hv * hv;
  sm.hsq[tid] = vsq;
  __syncthreads();
  int sel1 = rankTop64(sm, vsq, tid);
  float mpv = mask[tid];
  if (first){
    mask[tid] = (float)sel1;
    compactSel(sm, sel1, hv);
  } else {
    int st = sm.smask_t;
    float interv = mpv * (float)sel1;
    if (interv > 0.f && !st){
      float dd = hv - (1.f - interv);
      lossAcc += dd * dd;
    }
    float h2 = (mpv > 0.f) ? 0.f : hv;
    __syncthreads();               // rank1 readers done before hsq rewrite
    sm.hsq[tid] = h2 * h2;
    __syncthreads();
    int sel2 = rankTop64(sm, h2 * h2, tid);
    mask[tid] = mpv + (float)sel2;
    compactSel(sm, sel2, h2);
  }
  // compactSel ends with a barrier -> dlist/dval ready

  // sparse decode over the exactly-64 selected rows (ascending idx => bit-exact):
  // ext[d] = bdec[d] + sum_{sel h asc} val_h * Wdec[h*160+d]; thread owns d = tid
  if (tid < 160){
    float a = bdec[tid];
    #pragma unroll 8
    for (int i = 0; i < 64; i++){
      int idx = sm.dlist[i];       // block-uniform broadcast
      float hval = sm.dval[i];
      a = fmaf(hval, Wdec[idx * 160 + tid], a);
    }
    sm.ext[tid] = a;
  }
  __syncthreads();

  float mv = fabsf((float)(theta - 79));
  bool gate = (mv > 40.0f);        // ETH
  if (tid < 80){
    float dec = sm.ext[ind + tid];
    dec_out[tid] = dec;            // residual update uses decoded output regardless of gates
    float diff = dec - target[tid];
    float l = (gate || sm.smask[tid]) ? 0.f : diff * diff;
    lossAcc += l / (mv + 1.0f);
  }
  __syncthreads();
}

__global__ void __launch_bounds__(64) zero_out_kernel(float* out){
  if (threadIdx.x == 0) out[0] = 0.f;
}

// Pre-repack We into MFMA B-fragment layout (bf16 hi and lo), one 16B frag per lane per tile.
__global__ void __launch_bounds__(64) prep_we_kernel(
    const float* __restrict__ We, short8* __restrict__ bh, short8* __restrict__ bl){
  int tile = blockIdx.x;
  int lane = threadIdx.x;
  int kt = tile >> 4, nt = tile & 15;
  int k0 = kt * 32 + (lane >> 4) * 8;
  int n  = nt * 16 + (lane & 15);
  short8 h, l;
  #pragma unroll
  for (int j = 0; j < 8; j++){
    float v = We[(k0 + j) * 256 + n];
    unsigned bits = __float_as_uint(v);
    unsigned hi = bits >> 16;
    float hif = __uint_as_float(hi << 16);
    unsigned lo = __float_as_uint(v - hif) >> 16;
    h[j] = (short)hi; l[j] = (short)lo;
  }
  bh[tile * 64 + lane] = h;
  bl[tile * 64 + lane] = l;
}

template<int USE_WS>
__global__ void __launch_bounds__(256, 4) net_kernel(
    const float* __restrict__ x,  const float* __restrict__ y,
    const float* __restrict__ We, const float* __restrict__ be,
    const float* __restrict__ Wd, const float* __restrict__ bd,
    const float* __restrict__ Wds,const float* __restrict__ bds,
    const short8* __restrict__ wsBh, const short8* __restrict__ wsBl,
    float* out)
{
  __shared__ SM sm;
  int tid = threadIdx.x;
  int lane = tid & 63, w = tid >> 6;
  int bt  = blockIdx.x;
  const float* xin = x + bt * 80;
  const float* yin = y + bt * 80;

  if (tid < 80){
    sm.xres[tid] = xin[tid];
    float yv = yin[tid];
    sm.yres[tid] = yv;
    sm.smask[tid] = (yv == 0.f) ? 1 : 0;   // seq_mask from ORIGINAL y
  }
  sm.mp_self[tid] = 0.f;
  sm.mp_src[tid]  = 0.f;
  sm.beL[tid] = be[tid];
  __syncthreads();
  if (w == 0){
    int c = 0;
    for (int i = lane; i < 80; i += 64) c += (int)sm.smask[i];
    int total = waveSumI(c);
    if (lane == 0) sm.smask_t = (total == 80) ? 1 : 0;
  }
  __syncthreads();

  float lossAcc = 0.f;

  for (int it = 0; it < 4; it++){
    bool first = (it == 0);

    // --- align x_res to y_res ---
    int th1 = simArgmax(sm, sm.xres, sm.yal);

    // --- attention softmax(y_al * y_res) and z = y_al * attn ---
    // order-sensitive sum: wave 0 runs the byte-identical legacy code
    if (w == 0){
      float p0 = sm.yal[lane] * sm.yres[lane];
      float p1 = (lane < 16) ? sm.yal[64 + lane] * sm.yres[64 + lane] : -INFINITY;
      float mx = waveMax(fmaxf(p0, p1));
      float e0 = expf(p0 - mx);
      float e1 = (lane < 16) ? expf(p1 - mx) : 0.f;
      float ssum = waveSum(e0 + e1);
      sm.zb[lane] = sm.yal[lane] * (e0 / ssum);
      if (lane < 16) sm.zb[64 + lane] = sm.yal[64 + lane] * (e1 / ssum);
    }
    __syncthreads();

    // --- reverse shift: x_ele[d] = z[d + 79 - theta] ---
    if (tid < 80){
      int q = tid + 79 - th1;
      sm.xele[tid] = (q >= 0 && q < 80) ? sm.zb[q] : 0.f;
    }

    // --- self branch ---
    branchCompute<USE_WS>(sm, We, wsBh, wsBl, Wds, bds,
                          sm.xele, sm.mp_self, sm.xres, sm.xele, th1, first, lossAcc);

    // --- re-align decoded x_ele to y_res ---
    int th2 = simArgmax(sm, sm.xele, sm.yal);

    // --- src branch ---
    branchCompute<USE_WS>(sm, We, wsBh, wsBl, Wd, bd,
                          sm.yal, sm.mp_src, sm.yres, sm.decsrc, th2, first, lossAcc);

    // --- residual updates ---
    __syncthreads();
    if (tid < 80){
      sm.xres[tid] -= sm.xele[tid];
      sm.yres[tid] -= sm.decsrc[tid];
    }
    __syncthreads();
  }

  // block loss reduction: per-wave butterfly, then fixed-order 4-way sum
  float vsum = waveSum(lossAcc);
  if (lane == 0) sm.abv[w] = vsum;
  __syncthreads();
  if (tid == 0){
    float total = ((sm.abv[0] + sm.abv[1]) + sm.abv[2]) + sm.abv[3];
    atomicAdd(out, total * 0.25f);   // mean over 4 iterations
  }
}

extern "C" void kernel_launch(void* const* d_in, const int* in_sizes, int n_in,
                              void* d_out, int out_size, void* d_ws, size_t ws_size,
                              hipStream_t stream) {
  const float* x   = (const float*)d_in[0];
  const float* y   = (const float*)d_in[1];
  const float* We  = (const float*)d_in[2];
  const float* be  = (const float*)d_in[3];
  const float* Wd  = (const float*)d_in[4];
  const float* bd  = (const float*)d_in[5];
  const float* Wds = (const float*)d_in[6];
  const float* bds = (const float*)d_in[7];
  float* out = (float*)d_out;

  // We-fragment repack buffers: 80 tiles x 64 lanes x 16B each for hi and lo
  const size_t fragCount = 80 * 64;                     // short8 elements per buffer
  const size_t fragBytes = fragCount * sizeof(short8);  // 81920 B
  int use_ws = (ws_size >= 2 * fragBytes) ? 1 : 0;
  short8* wsBh = (short8*)d_ws;
  short8* wsBl = wsBh + fragCount;

  hipLaunchKernelGGL(zero_out_kernel, dim3(1), dim3(64), 0, stream, out);
  if (use_ws){
    hipLaunchKernelGGL(prep_we_kernel, dim3(80), dim3(64), 0, stream, We, wsBh, wsBl);
    hipLaunchKernelGGL((net_kernel<1>), dim3(NBT), dim3(256), 0, stream,
                       x, y, We, be, Wd, bd, Wds, bds, wsBh, wsBl, out);
  } else {
    hipLaunchKernelGGL((net_kernel<0>), dim3(NBT), dim3(256), 0, stream,
                       x, y, We, be, Wd, bd, Wds, bds, wsBh, wsBl, out);
  }
}

// Round 7
// 672.852 us; speedup vs baseline: 3.1097x; 1.1937x over previous
//
#include <hip/hip_runtime.h>
#include <math.h>

// Problem constants (B=8, T=256 -> 2048 independent (b,t) pipelines)
// R12 (resubmit after infra failure): integer-key rank. R11 (803 us) showed
// VALU issue is the dominant pipe (VALUBusy 62.7%); rankTop64's 14 calls x
// 256 float compares with tie-break (~4-5 VALU each) are ~35-40% of VALU
// work. All ranked values are squares (>= 0) -> IEEE bits are monotone ->
// key = (bits<<8)|(255-j) makes (key_i > key_j) EXACTLY the legacy
// predicate incl. top_k tie rule. One 64-bit compare + carry-add per
// element (~2 VALU). Bit-identical selection; everything else unchanged
// from R11 (bound (256,4), no spill).
#define NBT 2048

typedef __attribute__((ext_vector_type(8))) short short8;     // 8 bf16 (4 VGPRs)
typedef __attribute__((ext_vector_type(4))) float floatx4;    // MFMA C/D

struct SM {
  alignas(16) float xp[240];        // zero-padded encoder input (nonzero in [80,160))
  alignas(16) unsigned xhl[256];    // packed bf16: hi | lo<<16, zero-padded to 256
  alignas(16) unsigned long long hkey[256]; // rank keys: (bits(v)<<8)|(255-j)
  alignas(16) float yres[80];
  alignas(16) float beL[256];       // encoder bias staged in LDS
  alignas(16) float spad[240];      // padded buffer for sim windows
  alignas(16) float dval[64];       // compacted selected hidden values (ascending idx)
  alignas(16) int   dlist[64];      // compacted selected hidden indices (ascending)
  alignas(16) float energyP[4][96]; // per-wave (per-ng) energy partials
  float xres[80];
  float yal[80];
  float xele[80];
  float decsrc[80];
  float zb[80];
  float energy[96];                 // 81 valid + pad (6 m-tiles of 16)
  float mp_self[256];
  float mp_src[256];
  float ext[160];
  unsigned char smask[80];
  int smask_t;
  // cross-wave scratch
  float abv[4];
  int   abi[4];
  int   wcnt[4];
  float nys;
};

// ---- wave-level primitives (64 lanes, butterfly -> all lanes hold result) ----
__device__ __forceinline__ float waveSum(float v){
  #pragma unroll
  for (int off = 32; off > 0; off >>= 1) v += __shfl_xor(v, off, 64);
  return v;
}
__device__ __forceinline__ int waveSumI(int v){
  #pragma unroll
  for (int off = 32; off > 0; off >>= 1) v += __shfl_xor(v, off, 64);
  return v;
}
__device__ __forceinline__ float waveMax(float v){
  #pragma unroll
  for (int off = 32; off > 0; off >>= 1) v = fmaxf(v, __shfl_xor(v, off, 64));
  return v;
}

// block-wide argmax, JAX tie rule (lowest index wins). Max + min-index is
// associative, so any reduction structure yields the unique answer.
// All 256 threads must call; all return the winning index.
__device__ __forceinline__ int blockArgMax(SM& sm, float v, int idx){
  int lane = threadIdx.x & 63, w = threadIdx.x >> 6;
  #pragma unroll
  for (int off = 32; off > 0; off >>= 1){
    float ov = __shfl_xor(v,   off, 64);
    int   oi = __shfl_xor(idx, off, 64);
    if (ov > v || (ov == v && oi < idx)){ v = ov; idx = oi; }
  }
  if (lane == 0){ sm.abv[w] = v; sm.abi[w] = idx; }
  __syncthreads();
  float bv = sm.abv[0]; int bi = sm.abi[0];
  #pragma unroll
  for (int w2 = 1; w2 < 4; w2++){
    float ov = sm.abv[w2]; int oi = sm.abi[w2];
    if (ov > bv || (ov == bv && oi < bi)){ bv = ov; bi = oi; }
  }
  __syncthreads();   // abv/abi free for reuse after this
  return bi;
}

// top-64 membership via rank over integer keys. v >= 0 (squares) => IEEE
// bits monotone => key_i > key_j  <=>  v_i > v_j || (v_i==v_j && i<j).
// rank = #{key_i > key_j}; selected iff rank < 64. Exactly 64 selected
// (keys are unique by index). hkey reads are block-uniform -> broadcast.
__device__ __forceinline__ int rankTop64(SM& sm, unsigned long long mykey){
  int cnt = 0;
  const ulonglong2* q2 = (const ulonglong2*)sm.hkey;
  #pragma unroll 8
  for (int i2 = 0; i2 < 128; i2++){
    ulonglong2 o = q2[i2];
    cnt += (o.x > mykey) ? 1 : 0;
    cnt += (o.y > mykey) ? 1 : 0;
  }
  return (cnt < 64) ? 1 : 0;
}
__device__ __forceinline__ unsigned long long rankKey(float vsq, int j){
  return (((unsigned long long)__float_as_uint(vsq)) << 8)
       | (unsigned long long)(255 - j);
}

// Compact the exactly-64 selected (index,value) pairs into ascending-index LDS
// lists: per-wave ballot + cross-wave popcount prefix. Ascending order =>
// decode accumulation order matches the reference bit-exactly.
__device__ __forceinline__ void compactSel(SM& sm, int sel, float val){
  int tid = threadIdx.x, lane = tid & 63, w = tid >> 6;
  unsigned long long mq = __ballot(sel != 0);
  if (lane == 0) sm.wcnt[w] = __popcll(mq);
  __syncthreads();
  int base = 0;
  #pragma unroll
  for (int i = 0; i < 4; i++) base += (i < w) ? sm.wcnt[i] : 0;
  if (sel){
    unsigned long long below = (lane == 0) ? 0ull : ((~0ull) >> (64 - lane));
    int pos = base + (int)__popcll(mq & below);
    sm.dlist[pos] = tid;
    sm.dval[pos]  = val;
  }
  __syncthreads();   // list ready
}

// sim_argmax: cosine sim over 159 shifts of src vs yres; thread t owns shift t.
// Per-shift fmaf chain order identical to legacy (bit-exact sims). nys is
// computed by wave 0 with the legacy butterfly (bit-exact).
__device__ __forceinline__ int simArgmax(SM& sm, const float* src, float* yal_out){
  int tid = threadIdx.x;
  int lane = tid & 63, w = tid >> 6;
  __syncthreads();
  if (tid < 240) sm.spad[tid] = (tid >= 79 && tid < 159) ? src[tid - 79] : 0.f;
  if (w == 0){
    float yv2 = 0.f;
    for (int i = lane; i < 80; i += 64){ float yv = sm.yres[i]; yv2 = fmaf(yv, yv, yv2); }
    float ny = sqrtf(waveSum(yv2));
    if (lane == 0) sm.nys = ny;
  }
  __syncthreads();
  float nys = sm.nys;
  float bv = -INFINITY; int bi = 0;
  if (tid < 159){
    const float4* y4p = (const float4*)sm.yres;
    float num = 0.f, nx = 0.f;
    for (int w4 = 0; w4 < 20; w4++){
      float4 yy = y4p[w4];
      int wb = w4 * 4;
      float xa0 = sm.spad[tid + wb + 0];
      float xa1 = sm.spad[tid + wb + 1];
      float xa2 = sm.spad[tid + wb + 2];
      float xa3 = sm.spad[tid + wb + 3];
      num = fmaf(xa0, yy.x, num); nx = fmaf(xa0, xa0, nx);
      num = fmaf(xa1, yy.y, num); nx = fmaf(xa1, xa1, nx);
      num = fmaf(xa2, yy.z, num); nx = fmaf(xa2, xa2, nx);
      num = fmaf(xa3, yy.w, num); nx = fmaf(xa3, xa3, nx);
    }
    bv = num / (sqrtf(nx) * nys + 1e-6f);
    bi = tid;
  }
  int th = blockArgMax(sm, bv, bi);
  if (tid < 80) yal_out[tid] = sm.spad[th + tid];
  __syncthreads();
  return th;
}

// One branch: MFMA energy (split bf16, kt-trimmed — bit-safe; wave w owns
// n-group w, partials summed in legacy ng order; B-frags streamed per n-tile
// to keep peak live registers below the spill line), argmax, exact fp32 row
// recompute (1 j/thread), hsr (integer-key rank), sparse decode (1 d/thread),
// masked loss.
template<int USE_WS>
__device__ __forceinline__ void branchCompute(
    SM& sm, const float* __restrict__ We,
    const short8* __restrict__ wsBh, const short8* __restrict__ wsBl,
    const float* __restrict__ Wdec, const float* __restrict__ bdec,
    const float* enc_in, float* mask, const float* target,
    float* dec_out, int theta, bool first, float& lossAcc)
{
  int tid = threadIdx.x;
  int lane = tid & 63, w = tid >> 6;
  int quad = lane >> 4, l15 = lane & 15;
  __syncthreads();
  {
    float v = (tid >= 80 && tid < 160) ? enc_in[tid - 80] : 0.f;
    if (tid < 240) sm.xp[tid] = v;
    unsigned bits = __float_as_uint(v);
    unsigned hi = bits >> 16;
    float hif = __uint_as_float(hi << 16);
    unsigned lo = __float_as_uint(v - hif) >> 16;
    sm.xhl[tid] = hi | (lo << 16);
  }
  __syncthreads();

  const floatx4 zero4 = {0.f, 0.f, 0.f, 0.f};
  const int ng = w;                  // wave w owns n-group w (4 n-tiles)

  #pragma unroll 1
  for (int mh = 0; mh < 3; mh++){    // 2 m-tiles per pass
    int ktlo = (mh == 0) ? 1 : 0;    // nonzero-support kt range for these m rows
    int kthi = 5 - mh;               // (skipped products are exactly 0 -> bit-safe)
    floatx4 acc[2][4];
    #pragma unroll
    for (int m2 = 0; m2 < 2; m2++)
      #pragma unroll
      for (int nt = 0; nt < 4; nt++) acc[m2][nt] = zero4;

    #pragma unroll 1
    for (int kt = ktlo; kt < kthi; kt++){
      // A fragments for this kt, both m-tiles (held across the nt stream)
      short8 Ah[2], Al[2];
      #pragma unroll
      for (int m2 = 0; m2 < 2; m2++){
        int mt = mh * 2 + m2;
        int base = mt * 16 + l15 + kt * 32 + quad * 8;
        short8 ah, al;
        #pragma unroll
        for (int j = 0; j < 8; j++){
          unsigned u = sm.xhl[base + j];
          ah[j] = (short)(u & 0xffffu);
          al[j] = (short)(u >> 16);
        }
        Ah[m2] = ah; Al[m2] = al;
      }
      // stream B per n-tile: only one (Bh,Bl) pair live at a time (x2 unroll)
      #pragma unroll 2
      for (int nt = 0; nt < 4; nt++){
        short8 Bh, Bl;
        int tileIdx = kt * 16 + (ng * 4 + nt);
        if (USE_WS){
          Bh = wsBh[tileIdx * 64 + lane];
          Bl = wsBl[tileIdx * 64 + lane];
        } else {
          short8 bh, bl;
          int k0 = kt * 32 + quad * 8;
          int n  = (ng * 4 + nt) * 16 + l15;
          #pragma unroll
          for (int j = 0; j < 8; j++){
            float v = We[(k0 + j) * 256 + n];
            unsigned bits = __float_as_uint(v);
            unsigned hi = bits >> 16;
            float hif = __uint_as_float(hi << 16);
            unsigned lo = __float_as_uint(v - hif) >> 16;
            bh[j] = (short)hi; bl[j] = (short)lo;
          }
          Bh = bh; Bl = bl;
        }
        // per-accumulator op order unchanged vs legacy: AhBh, AlBh, AhBl
        acc[0][nt] = __builtin_amdgcn_mfma_f32_16x16x32_bf16(Ah[0], Bh, acc[0][nt], 0, 0, 0);
        acc[0][nt] = __builtin_amdgcn_mfma_f32_16x16x32_bf16(Al[0], Bh, acc[0][nt], 0, 0, 0);
        acc[0][nt] = __builtin_amdgcn_mfma_f32_16x16x32_bf16(Ah[0], Bl, acc[0][nt], 0, 0, 0);
        acc[1][nt] = __builtin_amdgcn_mfma_f32_16x16x32_bf16(Ah[1], Bh, acc[1][nt], 0, 0, 0);
        acc[1][nt] = __builtin_amdgcn_mfma_f32_16x16x32_bf16(Al[1], Bh, acc[1][nt], 0, 0, 0);
        acc[1][nt] = __builtin_amdgcn_mfma_f32_16x16x32_bf16(Ah[1], Bl, acc[1][nt], 0, 0, 0);
      }
    }

    // epilogue: add bias, square, reduce this wave's 64 columns (l15 butterfly,
    // byte-identical to legacy per-ng computation)
    float bn[4];
    #pragma unroll
    for (int nt = 0; nt < 4; nt++) bn[nt] = sm.beL[(ng * 4 + nt) * 16 + l15];
    #pragma unroll
    for (int m2 = 0; m2 < 2; m2++){
      int mt = mh * 2 + m2;
      float er[4];
      #pragma unroll
      for (int r = 0; r < 4; r++){
        float s_ = 0.f;
        #pragma unroll
        for (int nt = 0; nt < 4; nt++){
          float hvv = acc[m2][nt][r] + bn[nt];
          s_ = fmaf(hvv, hvv, s_);
        }
        er[r] = s_;
      }
      #pragma unroll
      for (int x2 = 1; x2 < 16; x2 <<= 1){
        #pragma unroll
        for (int r = 0; r < 4; r++) er[r] += __shfl_xor(er[r], x2, 64);
      }
      if (l15 == 0){
        #pragma unroll
        for (int r = 0; r < 4; r++)
          sm.energyP[w][mt * 16 + quad * 4 + r] = er[r];
      }
    }
  }
  __syncthreads();
  // combine ng partials in legacy left-assoc ng order: (((ng0+ng1)+ng2)+ng3)
  if (tid < 96){
    float e = sm.energyP[0][tid];
    e += sm.energyP[1][tid];
    e += sm.energyP[2][tid];
    e += sm.energyP[3][tid];
    sm.energy[tid] = e;
  }
  __syncthreads();

  // argmax over 81 energies (padded rows >80 contain garbage — exclude them)
  float bvE = (tid < 81) ? sm.energy[tid] : -INFINITY;
  int   biE = (tid < 81) ? tid : 0;
  int ind = blockArgMax(sm, bvE, biE);

  // recompute selected row h[ind, j] EXACTLY in fp32; thread owns j = tid
  // (same per-j fmaf chain order as legacy -> bit-exact)
  int roff = 80 - ind;
  float hv = sm.beL[tid];
  #pragma unroll 4
  for (int w2 = 0; w2 < 80; w2++){
    float xv = sm.xp[80 + w2];
    hv = fmaf(xv, We[(w2 + roff) * 256 + tid], hv);
  }

  // hsr (thread's single j) — integer-key rank, bit-exact selection
  float vsq = hv * hv;
  unsigned long long myk = rankKey(vsq, tid);
  sm.hkey[tid] = myk;
  __syncthreads();
  int sel1 = rankTop64(sm, myk);
  float mpv = mask[tid];
  if (first){
    mask[tid] = (float)sel1;
    compactSel(sm, sel1, hv);
  } else {
    int st = sm.smask_t;
    float interv = mpv * (float)sel1;
    if (interv > 0.f && !st){
      float dd = hv - (1.f - interv);
      lossAcc += dd * dd;
    }
    float h2 = (mpv > 0.f) ? 0.f : hv;
    __syncthreads();               // rank1 readers done before hkey rewrite
    unsigned long long myk2 = rankKey(h2 * h2, tid);
    sm.hkey[tid] = myk2;
    __syncthreads();
    int sel2 = rankTop64(sm, myk2);
    mask[tid] = mpv + (float)sel2;
    compactSel(sm, sel2, h2);
  }
  // compactSel ends with a barrier -> dlist/dval ready

  // sparse decode over the exactly-64 selected rows (ascending idx => bit-exact):
  // ext[d] = bdec[d] + sum_{sel h asc} val_h * Wdec[h*160+d]; thread owns d = tid
  if (tid < 160){
    float a = bdec[tid];
    #pragma unroll 8
    for (int i = 0; i < 64; i++){
      int idx = sm.dlist[i];       // block-uniform broadcast
      float hval = sm.dval[i];
      a = fmaf(hval, Wdec[idx * 160 + tid], a);
    }
    sm.ext[tid] = a;
  }
  __syncthreads();

  float mv = fabsf((float)(theta - 79));
  bool gate = (mv > 40.0f);        // ETH
  if (tid < 80){
    float dec = sm.ext[ind + tid];
    dec_out[tid] = dec;            // residual update uses decoded output regardless of gates
    float diff = dec - target[tid];
    float l = (gate || sm.smask[tid]) ? 0.f : diff * diff;
    lossAcc += l / (mv + 1.0f);
  }
  __syncthreads();
}

__global__ void __launch_bounds__(64) zero_out_kernel(float* out){
  if (threadIdx.x == 0) out[0] = 0.f;
}

// Pre-repack We into MFMA B-fragment layout (bf16 hi and lo), one 16B frag per lane per tile.
__global__ void __launch_bounds__(64) prep_we_kernel(
    const float* __restrict__ We, short8* __restrict__ bh, short8* __restrict__ bl){
  int tile = blockIdx.x;
  int lane = threadIdx.x;
  int kt = tile >> 4, nt = tile & 15;
  int k0 = kt * 32 + (lane >> 4) * 8;
  int n  = nt * 16 + (lane & 15);
  short8 h, l;
  #pragma unroll
  for (int j = 0; j < 8; j++){
    float v = We[(k0 + j) * 256 + n];
    unsigned bits = __float_as_uint(v);
    unsigned hi = bits >> 16;
    float hif = __uint_as_float(hi << 16);
    unsigned lo = __float_as_uint(v - hif) >> 16;
    h[j] = (short)hi; l[j] = (short)lo;
  }
  bh[tile * 64 + lane] = h;
  bl[tile * 64 + lane] = l;
}

template<int USE_WS>
__global__ void __launch_bounds__(256, 4) net_kernel(
    const float* __restrict__ x,  const float* __restrict__ y,
    const float* __restrict__ We, const float* __restrict__ be,
    const float* __restrict__ Wd, const float* __restrict__ bd,
    const float* __restrict__ Wds,const float* __restrict__ bds,
    const short8* __restrict__ wsBh, const short8* __restrict__ wsBl,
    float* out)
{
  __shared__ SM sm;
  int tid = threadIdx.x;
  int lane = tid & 63, w = tid >> 6;
  int bt  = blockIdx.x;
  const float* xin = x + bt * 80;
  const float* yin = y + bt * 80;

  if (tid < 80){
    sm.xres[tid] = xin[tid];
    float yv = yin[tid];
    sm.yres[tid] = yv;
    sm.smask[tid] = (yv == 0.f) ? 1 : 0;   // seq_mask from ORIGINAL y
  }
  sm.mp_self[tid] = 0.f;
  sm.mp_src[tid]  = 0.f;
  sm.beL[tid] = be[tid];
  __syncthreads();
  if (w == 0){
    int c = 0;
    for (int i = lane; i < 80; i += 64) c += (int)sm.smask[i];
    int total = waveSumI(c);
    if (lane == 0) sm.smask_t = (total == 80) ? 1 : 0;
  }
  __syncthreads();

  float lossAcc = 0.f;

  for (int it = 0; it < 4; it++){
    bool first = (it == 0);

    // --- align x_res to y_res ---
    int th1 = simArgmax(sm, sm.xres, sm.yal);

    // --- attention softmax(y_al * y_res) and z = y_al * attn ---
    // order-sensitive sum: wave 0 runs the byte-identical legacy code
    if (w == 0){
      float p0 = sm.yal[lane] * sm.yres[lane];
      float p1 = (lane < 16) ? sm.yal[64 + lane] * sm.yres[64 + lane] : -INFINITY;
      float mx = waveMax(fmaxf(p0, p1));
      float e0 = expf(p0 - mx);
      float e1 = (lane < 16) ? expf(p1 - mx) : 0.f;
      float ssum = waveSum(e0 + e1);
      sm.zb[lane] = sm.yal[lane] * (e0 / ssum);
      if (lane < 16) sm.zb[64 + lane] = sm.yal[64 + lane] * (e1 / ssum);
    }
    __syncthreads();

    // --- reverse shift: x_ele[d] = z[d + 79 - theta] ---
    if (tid < 80){
      int q = tid + 79 - th1;
      sm.xele[tid] = (q >= 0 && q < 80) ? sm.zb[q] : 0.f;
    }

    // --- self branch ---
    branchCompute<USE_WS>(sm, We, wsBh, wsBl, Wds, bds,
                          sm.xele, sm.mp_self, sm.xres, sm.xele, th1, first, lossAcc);

    // --- re-align decoded x_ele to y_res ---
    int th2 = simArgmax(sm, sm.xele, sm.yal);

    // --- src branch ---
    branchCompute<USE_WS>(sm, We, wsBh, wsBl, Wd, bd,
                          sm.yal, sm.mp_src, sm.yres, sm.decsrc, th2, first, lossAcc);

    // --- residual updates ---
    __syncthreads();
    if (tid < 80){
      sm.xres[tid] -= sm.xele[tid];
      sm.yres[tid] -= sm.decsrc[tid];
    }
    __syncthreads();
  }

  // block loss reduction: per-wave butterfly, then fixed-order 4-way sum
  float vsum = waveSum(lossAcc);
  if (lane == 0) sm.abv[w] = vsum;
  __syncthreads();
  if (tid == 0){
    float total = ((sm.abv[0] + sm.abv[1]) + sm.abv[2]) + sm.abv[3];
    atomicAdd(out, total * 0.25f);   // mean over 4 iterations
  }
}

extern "C" void kernel_launch(void* const* d_in, const int* in_sizes, int n_in,
                              void* d_out, int out_size, void* d_ws, size_t ws_size,
                              hipStream_t stream) {
  const float* x   = (const float*)d_in[0];
  const float* y   = (const float*)d_in[1];
  const float* We  = (const float*)d_in[2];
  const float* be  = (const float*)d_in[3];
  const float* Wd  = (const float*)d_in[4];
  const float* bd  = (const float*)d_in[5];
  const float* Wds = (const float*)d_in[6];
  const float* bds = (const float*)d_in[7];
  float* out = (float*)d_out;

  // We-fragment repack buffers: 80 tiles x 64 lanes x 16B each for hi and lo
  const size_t fragCount = 80 * 64;                     // short8 elements per buffer
  const size_t fragBytes = fragCount * sizeof(short8);  // 81920 B
  int use_ws = (ws_size >= 2 * fragBytes) ? 1 : 0;
  short8* wsBh = (short8*)d_ws;
  short8* wsBl = wsBh + fragCount;

  hipLaunchKernelGGL(zero_out_kernel, dim3(1), dim3(64), 0, stream, out);
  if (use_ws){
    hipLaunchKernelGGL(prep_we_kernel, dim3(80), dim3(64), 0, stream, We, wsBh, wsBl);
    hipLaunchKernelGGL((net_kernel<1>), dim3(NBT), dim3(256), 0, stream,
                       x, y, We, be, Wd, bd, Wds, bds, wsBh, wsBl, out);
  } else {
    hipLaunchKernelGGL((net_kernel<0>), dim3(NBT), dim3(256), 0, stream,
                       x, y, We, be, Wd, bd, Wds, bds, wsBh, wsBl, out);
  }
}

// Round 8
// 641.477 us; speedup vs baseline: 3.2618x; 1.0489x over previous
//
#include <hip/hip_runtime.h>
#include <math.h>

// Problem constants (B=8, T=256 -> 2048 independent (b,t) pipelines)
// R13: issue-slot reduction bundle. R12 (673 us) is issue-bound (VALUBusy
// 60%, MfmaUtil 18%, HBM ~0, occupancy pinned at 4 blk/CU by the VGPR
// quantum). Cuts, all bit-exact:
//  1) A-fragments via 8 rotated LDS copies (stride 264 u16, 16B-aligned,
//     bank-staggered): one ds_read_b128 per fragment instead of
//     8 ds_read_b32 + 8 pack ops (A base l15+8*(quad+2mt+4kt) ≡ l15 mod 8).
//  2) decode list as packed int2 (idx, valbits): 1 ds_read_b64 per term.
//  3) interleaved B-fragment workspace [tile][lane][{h,l}]: one addr chain.
//  4) y-norm (nys) hoisted: computed once per iteration (yres invariant).
//  5) row-recompute unroll 4->8 (serial fmaf chain order unchanged).
#define NBT 2048

typedef __attribute__((ext_vector_type(8))) short short8;     // 8 bf16 (4 VGPRs)
typedef __attribute__((ext_vector_type(4))) float floatx4;    // MFMA C/D

struct SM {
  alignas(16) float xp[240];        // zero-padded encoder input (nonzero in [80,160))
  alignas(16) short xhr[8][264];    // rotated bf16-hi copies: xhr[c][i] = hi(xp[c+i])
  alignas(16) short xlr[8][264];    // rotated bf16-lo copies
  alignas(16) unsigned long long hkey[256]; // rank keys: (bits(v)<<8)|(255-j)
  alignas(16) float yres[80];
  alignas(16) float beL[256];       // encoder bias staged in LDS
  alignas(16) float spad[240];      // padded buffer for sim windows
  alignas(16) int2  dpair[64];      // compacted (idx, float-bits) ascending
  alignas(16) float energyP[4][96]; // per-wave (per-ng) energy partials
  float xres[80];
  float yal[80];
  float xele[80];
  float decsrc[80];
  float zb[80];
  float energy[96];                 // 81 valid + pad (6 m-tiles of 16)
  float mp_self[256];
  float mp_src[256];
  float ext[160];
  unsigned char smask[80];
  int smask_t;
  // cross-wave scratch
  float abv[4];
  int   abi[4];
  int   wcnt[4];
  float nys;
};

// ---- wave-level primitives (64 lanes, butterfly -> all lanes hold result) ----
__device__ __forceinline__ float waveSum(float v){
  #pragma unroll
  for (int off = 32; off > 0; off >>= 1) v += __shfl_xor(v, off, 64);
  return v;
}
__device__ __forceinline__ int waveSumI(int v){
  #pragma unroll
  for (int off = 32; off > 0; off >>= 1) v += __shfl_xor(v, off, 64);
  return v;
}
__device__ __forceinline__ float waveMax(float v){
  #pragma unroll
  for (int off = 32; off > 0; off >>= 1) v = fmaxf(v, __shfl_xor(v, off, 64));
  return v;
}

// block-wide argmax, JAX tie rule (lowest index wins). Max + min-index is
// associative, so any reduction structure yields the unique answer.
// All 256 threads must call; all return the winning index.
__device__ __forceinline__ int blockArgMax(SM& sm, float v, int idx){
  int lane = threadIdx.x & 63, w = threadIdx.x >> 6;
  #pragma unroll
  for (int off = 32; off > 0; off >>= 1){
    float ov = __shfl_xor(v,   off, 64);
    int   oi = __shfl_xor(idx, off, 64);
    if (ov > v || (ov == v && oi < idx)){ v = ov; idx = oi; }
  }
  if (lane == 0){ sm.abv[w] = v; sm.abi[w] = idx; }
  __syncthreads();
  float bv = sm.abv[0]; int bi = sm.abi[0];
  #pragma unroll
  for (int w2 = 1; w2 < 4; w2++){
    float ov = sm.abv[w2]; int oi = sm.abi[w2];
    if (ov > bv || (ov == bv && oi < bi)){ bv = ov; bi = oi; }
  }
  __syncthreads();   // abv/abi free for reuse after this
  return bi;
}

// top-64 membership via rank over integer keys. v >= 0 (squares) => IEEE
// bits monotone => key_i > key_j  <=>  v_i > v_j || (v_i==v_j && i<j).
// rank = #{key_i > key_j}; selected iff rank < 64. Exactly 64 selected
// (keys are unique by index). hkey reads are block-uniform -> broadcast.
__device__ __forceinline__ int rankTop64(SM& sm, unsigned long long mykey){
  int cnt = 0;
  const ulonglong2* q2 = (const ulonglong2*)sm.hkey;
  #pragma unroll 8
  for (int i2 = 0; i2 < 128; i2++){
    ulonglong2 o = q2[i2];
    cnt += (o.x > mykey) ? 1 : 0;
    cnt += (o.y > mykey) ? 1 : 0;
  }
  return (cnt < 64) ? 1 : 0;
}
__device__ __forceinline__ unsigned long long rankKey(float vsq, int j){
  return (((unsigned long long)__float_as_uint(vsq)) << 8)
       | (unsigned long long)(255 - j);
}

// Compact the exactly-64 selected (index,value) pairs into an ascending-index
// LDS list: per-wave ballot + cross-wave popcount prefix. Ascending order =>
// decode accumulation order matches the reference bit-exactly.
__device__ __forceinline__ void compactSel(SM& sm, int sel, float val){
  int tid = threadIdx.x, lane = tid & 63, w = tid >> 6;
  unsigned long long mq = __ballot(sel != 0);
  if (lane == 0) sm.wcnt[w] = __popcll(mq);
  __syncthreads();
  int base = 0;
  #pragma unroll
  for (int i = 0; i < 4; i++) base += (i < w) ? sm.wcnt[i] : 0;
  if (sel){
    unsigned long long below = (lane == 0) ? 0ull : ((~0ull) >> (64 - lane));
    int pos = base + (int)__popcll(mq & below);
    sm.dpair[pos] = make_int2(tid, __float_as_int(val));
  }
  __syncthreads();   // list ready
}

// sim_argmax: cosine sim over 159 shifts of src vs yres; thread t owns shift t.
// Per-shift fmaf chain order identical to legacy (bit-exact sims). nys is
// computed by wave 0 (legacy butterfly, bit-exact) only when doNy != 0 —
// yres is invariant within an iteration, so sim2 reuses sim1's nys.
__device__ __forceinline__ int simArgmax(SM& sm, const float* src, float* yal_out, int doNy){
  int tid = threadIdx.x;
  int lane = tid & 63, w = tid >> 6;
  __syncthreads();
  if (tid < 240) sm.spad[tid] = (tid >= 79 && tid < 159) ? src[tid - 79] : 0.f;
  if (doNy && w == 0){
    float yv2 = 0.f;
    for (int i = lane; i < 80; i += 64){ float yv = sm.yres[i]; yv2 = fmaf(yv, yv, yv2); }
    float ny = sqrtf(waveSum(yv2));
    if (lane == 0) sm.nys = ny;
  }
  __syncthreads();
  float nys = sm.nys;
  float bv = -INFINITY; int bi = 0;
  if (tid < 159){
    const float4* y4p = (const float4*)sm.yres;
    float num = 0.f, nx = 0.f;
    for (int w4 = 0; w4 < 20; w4++){
      float4 yy = y4p[w4];
      int wb = w4 * 4;
      float xa0 = sm.spad[tid + wb + 0];
      float xa1 = sm.spad[tid + wb + 1];
      float xa2 = sm.spad[tid + wb + 2];
      float xa3 = sm.spad[tid + wb + 3];
      num = fmaf(xa0, yy.x, num); nx = fmaf(xa0, xa0, nx);
      num = fmaf(xa1, yy.y, num); nx = fmaf(xa1, xa1, nx);
      num = fmaf(xa2, yy.z, num); nx = fmaf(xa2, xa2, nx);
      num = fmaf(xa3, yy.w, num); nx = fmaf(xa3, xa3, nx);
    }
    bv = num / (sqrtf(nx) * nys + 1e-6f);
    bi = tid;
  }
  int th = blockArgMax(sm, bv, bi);
  if (tid < 80) yal_out[tid] = sm.spad[th + tid];
  __syncthreads();
  return th;
}

// One branch: MFMA energy (split bf16, kt-trimmed — bit-safe; wave w owns
// n-group w, partials summed in legacy ng order; A-frags read as single
// aligned b128 from rotated copies; B-frags streamed per n-tile), argmax,
// exact fp32 row recompute (1 j/thread), hsr (integer-key rank), sparse
// decode (1 d/thread), masked loss.
template<int USE_WS>
__device__ __forceinline__ void branchCompute(
    SM& sm, const float* __restrict__ We,
    const short8* __restrict__ wsB,
    const float* __restrict__ Wdec, const float* __restrict__ bdec,
    const float* enc_in, float* mask, const float* target,
    float* dec_out, int theta, bool first, float& lossAcc)
{
  int tid = threadIdx.x;
  int lane = tid & 63, w = tid >> 6;
  int quad = lane >> 4, l15 = lane & 15;
  __syncthreads();
  {
    float v = (tid >= 80 && tid < 160) ? enc_in[tid - 80] : 0.f;
    if (tid < 240) sm.xp[tid] = v;
    unsigned bits = __float_as_uint(v);
    unsigned hi = bits >> 16;
    float hif = __uint_as_float(hi << 16);
    unsigned lo = __float_as_uint(v - hif) >> 16;
    short hs = (short)hi, ls = (short)lo;
    // rotated copies: xhr[c][i] = hi(xp[c+i]); A-frag base ≡ l15 (mod 8)
    // -> each fragment is one aligned 16B read. Values bit-identical.
    #pragma unroll
    for (int c = 0; c < 8; c++){
      int i = tid - c;
      if (i >= 0){ sm.xhr[c][i] = hs; sm.xlr[c][i] = ls; }
    }
  }
  __syncthreads();

  const floatx4 zero4 = {0.f, 0.f, 0.f, 0.f};
  const int ng = w;                  // wave w owns n-group w (4 n-tiles)
  const int c8 = l15 & 7;
  const int hb = l15 >> 3;

  #pragma unroll 1
  for (int mh = 0; mh < 3; mh++){    // 2 m-tiles per pass
    int ktlo = (mh == 0) ? 1 : 0;    // nonzero-support kt range for these m rows
    int kthi = 5 - mh;               // (skipped products are exactly 0 -> bit-safe)
    floatx4 acc[2][4];
    #pragma unroll
    for (int m2 = 0; m2 < 2; m2++)
      #pragma unroll
      for (int nt = 0; nt < 4; nt++) acc[m2][nt] = zero4;

    #pragma unroll 1
    for (int kt = ktlo; kt < kthi; kt++){
      // A fragments for this kt, both m-tiles: single aligned b128 each.
      // base = mt*16 + l15 + kt*32 + quad*8 = (l15&7) + 8*kb
      short8 Ah[2], Al[2];
      #pragma unroll
      for (int m2 = 0; m2 < 2; m2++){
        int mt = mh * 2 + m2;
        int kb = quad + 2 * mt + 4 * kt + hb;
        Ah[m2] = *reinterpret_cast<const short8*>(&sm.xhr[c8][8 * kb]);
        Al[m2] = *reinterpret_cast<const short8*>(&sm.xlr[c8][8 * kb]);
      }
      // stream B per n-tile: only one (Bh,Bl) pair live at a time (x2 unroll)
      #pragma unroll 2
      for (int nt = 0; nt < 4; nt++){
        short8 Bh, Bl;
        int tileIdx = kt * 16 + (ng * 4 + nt);
        if (USE_WS){
          int ti2 = (tileIdx * 64 + lane) * 2;
          Bh = wsB[ti2];
          Bl = wsB[ti2 + 1];
        } else {
          short8 bh, bl;
          int k0 = kt * 32 + quad * 8;
          int n  = (ng * 4 + nt) * 16 + l15;
          #pragma unroll
          for (int j = 0; j < 8; j++){
            float v = We[(k0 + j) * 256 + n];
            unsigned bits = __float_as_uint(v);
            unsigned hi = bits >> 16;
            float hif = __uint_as_float(hi << 16);
            unsigned lo = __float_as_uint(v - hif) >> 16;
            bh[j] = (short)hi; bl[j] = (short)lo;
          }
          Bh = bh; Bl = bl;
        }
        // per-accumulator op order unchanged vs legacy: AhBh, AlBh, AhBl
        acc[0][nt] = __builtin_amdgcn_mfma_f32_16x16x32_bf16(Ah[0], Bh, acc[0][nt], 0, 0, 0);
        acc[0][nt] = __builtin_amdgcn_mfma_f32_16x16x32_bf16(Al[0], Bh, acc[0][nt], 0, 0, 0);
        acc[0][nt] = __builtin_amdgcn_mfma_f32_16x16x32_bf16(Ah[0], Bl, acc[0][nt], 0, 0, 0);
        acc[1][nt] = __builtin_amdgcn_mfma_f32_16x16x32_bf16(Ah[1], Bh, acc[1][nt], 0, 0, 0);
        acc[1][nt] = __builtin_amdgcn_mfma_f32_16x16x32_bf16(Al[1], Bh, acc[1][nt], 0, 0, 0);
        acc[1][nt] = __builtin_amdgcn_mfma_f32_16x16x32_bf16(Ah[1], Bl, acc[1][nt], 0, 0, 0);
      }
    }

    // epilogue: add bias, square, reduce this wave's 64 columns (l15 butterfly,
    // byte-identical to legacy per-ng computation)
    float bn[4];
    #pragma unroll
    for (int nt = 0; nt < 4; nt++) bn[nt] = sm.beL[(ng * 4 + nt) * 16 + l15];
    #pragma unroll
    for (int m2 = 0; m2 < 2; m2++){
      int mt = mh * 2 + m2;
      float er[4];
      #pragma unroll
      for (int r = 0; r < 4; r++){
        float s_ = 0.f;
        #pragma unroll
        for (int nt = 0; nt < 4; nt++){
          float hvv = acc[m2][nt][r] + bn[nt];
          s_ = fmaf(hvv, hvv, s_);
        }
        er[r] = s_;
      }
      #pragma unroll
      for (int x2 = 1; x2 < 16; x2 <<= 1){
        #pragma unroll
        for (int r = 0; r < 4; r++) er[r] += __shfl_xor(er[r], x2, 64);
      }
      if (l15 == 0){
        #pragma unroll
        for (int r = 0; r < 4; r++)
          sm.energyP[w][mt * 16 + quad * 4 + r] = er[r];
      }
    }
  }
  __syncthreads();
  // combine ng partials in legacy left-assoc ng order: (((ng0+ng1)+ng2)+ng3)
  if (tid < 96){
    float e = sm.energyP[0][tid];
    e += sm.energyP[1][tid];
    e += sm.energyP[2][tid];
    e += sm.energyP[3][tid];
    sm.energy[tid] = e;
  }
  __syncthreads();

  // argmax over 81 energies (padded rows >80 contain garbage — exclude them)
  float bvE = (tid < 81) ? sm.energy[tid] : -INFINITY;
  int   biE = (tid < 81) ? tid : 0;
  int ind = blockArgMax(sm, bvE, biE);

  // recompute selected row h[ind, j] EXACTLY in fp32; thread owns j = tid
  // (same per-j fmaf chain order as legacy -> bit-exact; unroll only deepens
  // the load pipeline, chain order untouched)
  int roff = 80 - ind;
  float hv = sm.beL[tid];
  #pragma unroll 8
  for (int w2 = 0; w2 < 80; w2++){
    float xv = sm.xp[80 + w2];
    hv = fmaf(xv, We[(w2 + roff) * 256 + tid], hv);
  }

  // hsr (thread's single j) — integer-key rank, bit-exact selection
  float vsq = hv * hv;
  unsigned long long myk = rankKey(vsq, tid);
  sm.hkey[tid] = myk;
  __syncthreads();
  int sel1 = rankTop64(sm, myk);
  float mpv = mask[tid];
  if (first){
    mask[tid] = (float)sel1;
    compactSel(sm, sel1, hv);
  } else {
    int st = sm.smask_t;
    float interv = mpv * (float)sel1;
    if (interv > 0.f && !st){
      float dd = hv - (1.f - interv);
      lossAcc += dd * dd;
    }
    float h2 = (mpv > 0.f) ? 0.f : hv;
    __syncthreads();               // rank1 readers done before hkey rewrite
    unsigned long long myk2 = rankKey(h2 * h2, tid);
    sm.hkey[tid] = myk2;
    __syncthreads();
    int sel2 = rankTop64(sm, myk2);
    mask[tid] = mpv + (float)sel2;
    compactSel(sm, sel2, h2);
  }
  // compactSel ends with a barrier -> dpair ready

  // sparse decode over the exactly-64 selected rows (ascending idx => bit-exact):
  // ext[d] = bdec[d] + sum_{sel h asc} val_h * Wdec[h*160+d]; thread owns d = tid
  if (tid < 160){
    float a = bdec[tid];
    #pragma unroll 8
    for (int i = 0; i < 64; i++){
      int2 p = sm.dpair[i];        // block-uniform broadcast, one b64 read
      a = fmaf(__int_as_float(p.y), Wdec[p.x * 160 + tid], a);
    }
    sm.ext[tid] = a;
  }
  __syncthreads();

  float mv = fabsf((float)(theta - 79));
  bool gate = (mv > 40.0f);        // ETH
  if (tid < 80){
    float dec = sm.ext[ind + tid];
    dec_out[tid] = dec;            // residual update uses decoded output regardless of gates
    float diff = dec - target[tid];
    float l = (gate || sm.smask[tid]) ? 0.f : diff * diff;
    lossAcc += l / (mv + 1.0f);
  }
  __syncthreads();
}

__global__ void __launch_bounds__(64) zero_out_kernel(float* out){
  if (threadIdx.x == 0) out[0] = 0.f;
}

// Pre-repack We into MFMA B-fragment layout (bf16 hi and lo, interleaved):
// wsB[(tile*64+lane)*2 + {0,1}] = {hi, lo} fragment (16B each).
__global__ void __launch_bounds__(64) prep_we_kernel(
    const float* __restrict__ We, short8* __restrict__ wsB){
  int tile = blockIdx.x;
  int lane = threadIdx.x;
  int kt = tile >> 4, nt = tile & 15;
  int k0 = kt * 32 + (lane >> 4) * 8;
  int n  = nt * 16 + (lane & 15);
  short8 h, l;
  #pragma unroll
  for (int j = 0; j < 8; j++){
    float v = We[(k0 + j) * 256 + n];
    unsigned bits = __float_as_uint(v);
    unsigned hi = bits >> 16;
    float hif = __uint_as_float(hi << 16);
    unsigned lo = __float_as_uint(v - hif) >> 16;
    h[j] = (short)hi; l[j] = (short)lo;
  }
  int ti2 = (tile * 64 + lane) * 2;
  wsB[ti2]     = h;
  wsB[ti2 + 1] = l;
}

template<int USE_WS>
__global__ void __launch_bounds__(256, 4) net_kernel(
    const float* __restrict__ x,  const float* __restrict__ y,
    const float* __restrict__ We, const float* __restrict__ be,
    const float* __restrict__ Wd, const float* __restrict__ bd,
    const float* __restrict__ Wds,const float* __restrict__ bds,
    const short8* __restrict__ wsB,
    float* out)
{
  __shared__ SM sm;
  int tid = threadIdx.x;
  int lane = tid & 63, w = tid >> 6;
  int bt  = blockIdx.x;
  const float* xin = x + bt * 80;
  const float* yin = y + bt * 80;

  if (tid < 80){
    sm.xres[tid] = xin[tid];
    float yv = yin[tid];
    sm.yres[tid] = yv;
    sm.smask[tid] = (yv == 0.f) ? 1 : 0;   // seq_mask from ORIGINAL y
  }
  sm.mp_self[tid] = 0.f;
  sm.mp_src[tid]  = 0.f;
  sm.beL[tid] = be[tid];
  __syncthreads();
  if (w == 0){
    int c = 0;
    for (int i = lane; i < 80; i += 64) c += (int)sm.smask[i];
    int total = waveSumI(c);
    if (lane == 0) sm.smask_t = (total == 80) ? 1 : 0;
  }
  __syncthreads();

  float lossAcc = 0.f;

  for (int it = 0; it < 4; it++){
    bool first = (it == 0);

    // --- align x_res to y_res (computes nys for this iteration) ---
    int th1 = simArgmax(sm, sm.xres, sm.yal, 1);

    // --- attention softmax(y_al * y_res) and z = y_al * attn ---
    // order-sensitive sum: wave 0 runs the byte-identical legacy code
    if (w == 0){
      float p0 = sm.yal[lane] * sm.yres[lane];
      float p1 = (lane < 16) ? sm.yal[64 + lane] * sm.yres[64 + lane] : -INFINITY;
      float mx = waveMax(fmaxf(p0, p1));
      float e0 = expf(p0 - mx);
      float e1 = (lane < 16) ? expf(p1 - mx) : 0.f;
      float ssum = waveSum(e0 + e1);
      sm.zb[lane] = sm.yal[lane] * (e0 / ssum);
      if (lane < 16) sm.zb[64 + lane] = sm.yal[64 + lane] * (e1 / ssum);
    }
    __syncthreads();

    // --- reverse shift: x_ele[d] = z[d + 79 - theta] ---
    if (tid < 80){
      int q = tid + 79 - th1;
      sm.xele[tid] = (q >= 0 && q < 80) ? sm.zb[q] : 0.f;
    }

    // --- self branch ---
    branchCompute<USE_WS>(sm, We, wsB, Wds, bds,
                          sm.xele, sm.mp_self, sm.xres, sm.xele, th1, first, lossAcc);

    // --- re-align decoded x_ele to y_res (yres unchanged -> reuse nys) ---
    int th2 = simArgmax(sm, sm.xele, sm.yal, 0);

    // --- src branch ---
    branchCompute<USE_WS>(sm, We, wsB, Wd, bd,
                          sm.yal, sm.mp_src, sm.yres, sm.decsrc, th2, first, lossAcc);

    // --- residual updates ---
    __syncthreads();
    if (tid < 80){
      sm.xres[tid] -= sm.xele[tid];
      sm.yres[tid] -= sm.decsrc[tid];
    }
    __syncthreads();
  }

  // block loss reduction: per-wave butterfly, then fixed-order 4-way sum
  float vsum = waveSum(lossAcc);
  if (lane == 0) sm.abv[w] = vsum;
  __syncthreads();
  if (tid == 0){
    float total = ((sm.abv[0] + sm.abv[1]) + sm.abv[2]) + sm.abv[3];
    atomicAdd(out, total * 0.25f);   // mean over 4 iterations
  }
}

extern "C" void kernel_launch(void* const* d_in, const int* in_sizes, int n_in,
                              void* d_out, int out_size, void* d_ws, size_t ws_size,
                              hipStream_t stream) {
  const float* x   = (const float*)d_in[0];
  const float* y   = (const float*)d_in[1];
  const float* We  = (const float*)d_in[2];
  const float* be  = (const float*)d_in[3];
  const float* Wd  = (const float*)d_in[4];
  const float* bd  = (const float*)d_in[5];
  const float* Wds = (const float*)d_in[6];
  const float* bds = (const float*)d_in[7];
  float* out = (float*)d_out;

  // We-fragment repack buffer: 80 tiles x 64 lanes x {hi,lo} x 16B = 160 KiB
  const size_t fragCount = 80 * 64 * 2;                 // short8 elements
  const size_t fragBytes = fragCount * sizeof(short8);  // 163840 B
  int use_ws = (ws_size >= fragBytes) ? 1 : 0;
  short8* wsB = (short8*)d_ws;

  hipLaunchKernelGGL(zero_out_kernel, dim3(1), dim3(64), 0, stream, out);
  if (use_ws){
    hipLaunchKernelGGL(prep_we_kernel, dim3(80), dim3(64), 0, stream, We, wsB);
    hipLaunchKernelGGL((net_kernel<1>), dim3(NBT), dim3(256), 0, stream,
                       x, y, We, be, Wd, bd, Wds, bds, wsB, out);
  } else {
    hipLaunchKernelGGL((net_kernel<0>), dim3(NBT), dim3(256), 0, stream,
                       x, y, We, be, Wd, bd, Wds, bds, wsB, out);
  }
}